// Round 9
// baseline (220.485 us; speedup 1.0000x reference)
//
#include <hip/hip_runtime.h>

#define T_TOK 2048
#define D_DIM 512
#define F_DIM 2048
#define E_NUM 8
#define BCAP 2048            // per-expert bucket capacity (worst case: all tokens)
#define LN_EPS 1e-5f

typedef __attribute__((ext_vector_type(8))) short bf16x8;
typedef __attribute__((ext_vector_type(4))) float floatx4;

static __device__ __forceinline__ ushort f2bf(float f) {
  union { float f; unsigned int u; } v; v.f = f;
  unsigned int u = v.u;
  return (ushort)((u + 0x7fffu + ((u >> 16) & 1u)) >> 16);  // RNE
}

// ---------------- combined weight transpose+convert (both W1 and W2), zeroes cnt ----------------
__global__ __launch_bounds__(256) void convT_kernel(
    const float* __restrict__ W1, const float* __restrict__ W2,
    ushort* __restrict__ W1T, ushort* __restrict__ W2T, int* __restrict__ cnt) {
  if (blockIdx.x == 0 && blockIdx.y == 0 && blockIdx.z == 0 && threadIdx.x < E_NUM)
    cnt[threadIdx.x] = 0;  // visible to front_kernel at dispatch boundary
  const float* src; ushort* dst; int R, C, c0, r0;
  if (blockIdx.z < E_NUM) {
    src = W1 + (size_t)blockIdx.z * D_DIM * F_DIM;
    dst = W1T + (size_t)blockIdx.z * D_DIM * F_DIM;
    R = D_DIM; C = F_DIM;
    c0 = blockIdx.x * 64; r0 = blockIdx.y * 32;
  } else {
    src = W2 + (size_t)(blockIdx.z - E_NUM) * D_DIM * F_DIM;
    dst = W2T + (size_t)(blockIdx.z - E_NUM) * D_DIM * F_DIM;
    R = F_DIM; C = D_DIM;
    int idx = blockIdx.y * 32 + blockIdx.x;  // [0,512)
    c0 = (idx & 7) * 64; r0 = (idx >> 3) * 32;
  }
  __shared__ ushort tile[64][34];  // [c][r]
  int tid = threadIdx.x;
  int tc = (tid & 31) * 2, tr = tid >> 5;  // tr in [0,8)
#pragma unroll
  for (int rr = 0; rr < 32; rr += 8) {
    float2 v = *(const float2*)(src + (size_t)(r0 + tr + rr) * C + c0 + tc);
    tile[tc][tr + rr] = f2bf(v.x);
    tile[tc + 1][tr + rr] = f2bf(v.y);
  }
  __syncthreads();
  int wc = tid >> 4, wj = (tid & 15) * 2;
#pragma unroll
  for (int cc = 0; cc < 64; cc += 16) {
    uint v = (uint)tile[cc + wc][wj] | ((uint)tile[cc + wc][wj + 1] << 16);
    *(uint*)(dst + (size_t)(c0 + cc + wc) * R + r0 + wj) = v;
  }
}

// ---------------- fused front: router + bucket-scatter + LN apply ----------------
__global__ __launch_bounds__(256) void front_kernel(
    const float* __restrict__ x, const float* __restrict__ cent,
    const float* __restrict__ g, const float* __restrict__ b,
    int* __restrict__ cnt, float* __restrict__ alphav, int* __restrict__ eidv,
    int* __restrict__ tokof, ushort* __restrict__ h0p) {
  int wave = threadIdx.x >> 6, lane = threadIdx.x & 63;
  int t = blockIdx.x * 4 + wave;
  const float* xp = x + (size_t)t * D_DIM + lane * 8;
  float4 x0 = *(const float4*)xp, x1 = *(const float4*)(xp + 4);
  float xv[8] = {x0.x, x0.y, x0.z, x0.w, x1.x, x1.y, x1.z, x1.w};
  float s = 0.f, s2 = 0.f, cd[E_NUM];
#pragma unroll
  for (int j = 0; j < 8; j++) { s += xv[j]; s2 += xv[j] * xv[j]; }
#pragma unroll
  for (int e = 0; e < E_NUM; e++) {
    const float* cp = cent + (size_t)e * D_DIM + lane * 8;
    float4 c0 = *(const float4*)cp, c1 = *(const float4*)(cp + 4);
    float cv[8] = {c0.x, c0.y, c0.z, c0.w, c1.x, c1.y, c1.z, c1.w};
    float a = 0.f;
#pragma unroll
    for (int j = 0; j < 8; j++) a += xv[j] * cv[j];
    cd[e] = a;
  }
#pragma unroll
  for (int m = 1; m < 64; m <<= 1) {
    s  += __shfl_xor(s,  m, 64);
    s2 += __shfl_xor(s2, m, 64);
#pragma unroll
    for (int e = 0; e < E_NUM; e++) cd[e] += __shfl_xor(cd[e], m, 64);
  }
  float mu = s / (float)D_DIM;
  float var = s2 / (float)D_DIM - mu * mu;
  if (var < 0.f) var = 0.f;
  float rs = rsqrtf(var + LN_EPS);
  int best = 0;
#pragma unroll
  for (int e = 1; e < E_NUM; e++) if (cd[e] > cd[best]) best = e;  // first-max (np.argmax)
  int pos = 0;
  if (lane == 0) pos = atomicAdd(&cnt[best], 1);
  pos = __shfl(pos, 0, 64);
  if (lane == 0) {
    alphav[t] = 1.f / (1.f + expf(-cd[best]));
    eidv[t] = best;
    tokof[best * BCAP + pos] = t;
  }
  const float* gp = g + (size_t)best * D_DIM + lane * 8;
  const float* bp = b + (size_t)best * D_DIM + lane * 8;
  union { ushort u16[8]; uint4 v; } o;
#pragma unroll
  for (int j = 0; j < 8; j++)
    o.u16[j] = f2bf((xv[j] - mu) * rs * gp[j] + bp[j]);
  *(uint4*)(h0p + ((size_t)best * BCAP + pos) * D_DIM + lane * 8) = o.v;
}

// ---------------- final reduce: out = x + alpha * (sum of split-K partials + b2) ----------------
__global__ __launch_bounds__(128) void reduce_kernel(
    const float* __restrict__ P, const float* __restrict__ x, const float* __restrict__ b2,
    const int* __restrict__ eidv, const float* __restrict__ alphav,
    float* __restrict__ out) {
  int t = blockIdx.x;
  int e = eidv[t];
  float al = alphav[t];
  int c = threadIdx.x * 4;
  const size_t stride = (size_t)T_TOK * D_DIM;
  float4 s0 = *(const float4*)(P + (size_t)t * D_DIM + c);
  float4 s1 = *(const float4*)(P + stride + (size_t)t * D_DIM + c);
  float4 s2 = *(const float4*)(P + 2 * stride + (size_t)t * D_DIM + c);
  float4 s3 = *(const float4*)(P + 3 * stride + (size_t)t * D_DIM + c);
  float4 bv = *(const float4*)(b2 + (size_t)e * D_DIM + c);
  float4 xv = *(const float4*)(x + (size_t)t * D_DIM + c);
  float4 o;
  o.x = xv.x + al * (s0.x + s1.x + s2.x + s3.x + bv.x);
  o.y = xv.y + al * (s0.y + s1.y + s2.y + s3.y + bv.y);
  o.z = xv.z + al * (s0.z + s1.z + s2.z + s3.z + bv.z);
  o.w = xv.w + al * (s0.w + s1.w + s2.w + s3.w + bv.w);
  *(float4*)(out + (size_t)t * D_DIM + c) = o;
}

// ---------------- flatmm grouped GEMM: single-wave block, 64x64 tile, NO LDS, NO barriers ----------------
// Fragments loaded global->VGPR directly. Per instruction a wave reads 16 full
// 64B lines (fm=16 rows x quad=4 16B k-subchunks) -- line-perfect. Distance-2
// software prefetch (mod-3 register rotation), fully unrolled: hardware
// scoreboard pipelines k-windows with zero barrier drains.
// MODE 1: H[bucket] = relu(A*W1 + b1) bf16.  KTOT=512,  bx = nt in [0,32).
// MODE 2: Part[slice][t] = A*W2 slice-sum.   KTOT=2048, bx = slice*8 + nt.
// Rows >= ce hold finite poison (0xAA pattern ~1e-13); masked on store.
template<int KTOT, int NTOT, int MODE>
__global__ __launch_bounds__(64) void flat_gemm_kernel(
    const ushort* __restrict__ A, const ushort* __restrict__ BT,
    const float* __restrict__ bias, const int* __restrict__ cnt,
    const int* __restrict__ tokof,
    ushort* __restrict__ Hout, float* __restrict__ Pout) {
  constexpr int KITER = 16;  // 512-k window in 32-k steps
  int e = blockIdx.z, mt = blockIdx.y;
  int ce = cnt[e];
  if (mt * 64 >= ce) return;
  int bx = blockIdx.x;
  int nt = (MODE == 1) ? bx : (bx & 7);
  int k_base = (MODE == 1) ? 0 : (bx >> 3) * 512;
  int n0 = nt * 64;

  int lane = threadIdx.x;
  int fm = lane & 15, quad = lane >> 4;

  const ushort* ap[4];
  const ushort* bp[4];
#pragma unroll
  for (int i = 0; i < 4; i++)
    ap[i] = A + ((size_t)e * BCAP + mt * 64 + i * 16 + fm) * KTOT + k_base + quad * 8;
#pragma unroll
  for (int j = 0; j < 4; j++)
    bp[j] = BT + ((size_t)e * NTOT + n0 + j * 16 + fm) * KTOT + k_base + quad * 8;

  floatx4 acc[4][4];
#pragma unroll
  for (int i = 0; i < 4; i++)
#pragma unroll
    for (int j = 0; j < 4; j++) acc[i][j] = (floatx4){0.f, 0.f, 0.f, 0.f};

  // mod-3 register rotation, prefetch distance 2 (all indices static under full unroll)
  bf16x8 af[3][4], bf[3][4];
#pragma unroll
  for (int i = 0; i < 4; i++) {
    af[0][i] = *(const bf16x8*)(ap[i]);
    bf[0][i] = *(const bf16x8*)(bp[i]);
    af[1][i] = *(const bf16x8*)(ap[i] + 32);
    bf[1][i] = *(const bf16x8*)(bp[i] + 32);
  }

#pragma unroll
  for (int ki = 0; ki < KITER; ki++) {
    const int cur = ki % 3;
    const int pre = (ki + 2) % 3;
    if (ki + 2 < KITER) {
      const int k = (ki + 2) * 32;
#pragma unroll
      for (int i = 0; i < 4; i++) {
        af[pre][i] = *(const bf16x8*)(ap[i] + k);
        bf[pre][i] = *(const bf16x8*)(bp[i] + k);
      }
    }
#pragma unroll
    for (int mi = 0; mi < 4; mi++)
#pragma unroll
      for (int ni = 0; ni < 4; ni++)
        acc[mi][ni] = __builtin_amdgcn_mfma_f32_16x16x32_bf16(af[cur][mi], bf[cur][ni], acc[mi][ni], 0, 0, 0);
  }

  // C/D layout: col = lane&15, row = quad*4 + reg (m89/m91 verified)
#pragma unroll
  for (int mi = 0; mi < 4; mi++) {
    int lmb = mt * 64 + mi * 16 + quad * 4;
#pragma unroll
    for (int r = 0; r < 4; r++) {
      int lm = lmb + r;
      if (lm >= ce) continue;
      if (MODE == 1) {
        size_t row = (size_t)e * BCAP + lm;
#pragma unroll
        for (int ni = 0; ni < 4; ni++) {
          int gcol = n0 + ni * 16 + fm;
          float v = acc[mi][ni][r] + bias[e * NTOT + gcol];
          v = v > 0.f ? v : 0.f;
          Hout[row * NTOT + gcol] = f2bf(v);
        }
      } else {
        int t = tokof[e * BCAP + lm];
        float* dst = Pout + (size_t)(bx >> 3) * T_TOK * NTOT + (size_t)t * NTOT;
#pragma unroll
        for (int ni = 0; ni < 4; ni++)
          dst[n0 + ni * 16 + fm] = acc[mi][ni][r];
      }
    }
  }
}

extern "C" void kernel_launch(void* const* d_in, const int* in_sizes, int n_in,
                              void* d_out, int out_size, void* d_ws, size_t ws_size,
                              hipStream_t stream) {
  const float* x    = (const float*)d_in[0];
  const float* cent = (const float*)d_in[1];
  const float* ln_g = (const float*)d_in[2];
  const float* ln_b = (const float*)d_in[3];
  const float* W1   = (const float*)d_in[4];
  const float* b1   = (const float*)d_in[5];
  const float* W2   = (const float*)d_in[6];
  const float* b2   = (const float*)d_in[7];
  float* out = (float*)d_out;

  char* ws = (char*)d_ws;
  size_t off = 0;
  auto alloc = [&](size_t bytes) {
    char* p = ws + off;
    off += (bytes + 255) & ~(size_t)255;
    return p;
  };
  int*    cnt    = (int*)alloc(E_NUM * 4);
  float*  alphav = (float*)alloc(T_TOK * 4);
  int*    eidv   = (int*)alloc(T_TOK * 4);
  int*    tokof  = (int*)alloc((size_t)E_NUM * BCAP * 4);               // 64 KB
  ushort* h0p    = (ushort*)alloc((size_t)E_NUM * BCAP * D_DIM * 2);    // 16.8 MB bf16 buckets
  ushort* H      = (ushort*)alloc((size_t)E_NUM * BCAP * F_DIM * 2);    // 67 MB bf16 buckets
  ushort* W1T    = (ushort*)alloc((size_t)E_NUM * F_DIM * D_DIM * 2);   // 16.8 MB bf16 [E][F][D]
  ushort* W2T    = (ushort*)alloc((size_t)E_NUM * D_DIM * F_DIM * 2);   // 16.8 MB bf16 [E][D][F]
  float*  Part   = (float*)alloc((size_t)4 * T_TOK * D_DIM * 4);        // 16.8 MB f32, token-indexed

  // 1) weight convert/transpose (also zeroes cnt, before front in stream order)
  hipLaunchKernelGGL(convT_kernel, dim3(32, 16, 16), dim3(256), 0, stream,
                     W1, W2, W1T, W2T, cnt);
  // 2) fused router + bucket scatter + LN
  hipLaunchKernelGGL(front_kernel, dim3(T_TOK / 4), dim3(256), 0, stream,
                     x, cent, ln_g, ln_b, cnt, alphav, eidv, tokof, h0p);
  // 3) H = relu(h0 @ W1 + b1): flatmm, 64x64/wave, no LDS/barriers
  hipLaunchKernelGGL((flat_gemm_kernel<D_DIM, F_DIM, 1>),
                     dim3(F_DIM / 64, BCAP / 64, E_NUM), dim3(64), 0, stream,
                     h0p, W1T, b1, cnt, tokof, H, nullptr);
  // 4) Part[slice] = H @ W2 (raw partials): flatmm, split-K=4
  hipLaunchKernelGGL((flat_gemm_kernel<F_DIM, D_DIM, 2>),
                     dim3(8 * 4, BCAP / 64, E_NUM), dim3(64), 0, stream,
                     H, W2T, nullptr, cnt, tokof, nullptr, Part);
  // 5) out = x + alpha*(sum Part + b2)
  hipLaunchKernelGGL(reduce_kernel, dim3(T_TOK), dim3(128), 0, stream,
                     Part, x, b2, eidv, alphav, out);
}

// Round 10
// 198.374 us; speedup vs baseline: 1.1115x; 1.1115x over previous
//
#include <hip/hip_runtime.h>

#define T_TOK 2048
#define D_DIM 512
#define F_DIM 2048
#define E_NUM 8
#define LN_EPS 1e-5f

typedef __attribute__((ext_vector_type(8))) short bf16x8;
typedef __attribute__((ext_vector_type(4))) float floatx4;

static __device__ __forceinline__ ushort f2bf(float f) {
  union { float f; unsigned int u; } v; v.f = f;
  unsigned int u = v.u;
  return (ushort)((u + 0x7fffu + ((u >> 16) & 1u)) >> 16);  // RNE
}

static __device__ __forceinline__ void gld_lds16(const void* g, void* l) {
  __builtin_amdgcn_global_load_lds(
      (const __attribute__((address_space(1))) unsigned int*)g,
      (__attribute__((address_space(3))) unsigned int*)l, 16, 0, 0);
}

// ---------------- K1 "prep": weight convT (blocks 0..8191) + router (blocks 8192..8703) ----------------
// convT: z<8: W1 f32 [E][D][F] -> W1T bf16 [E][F][D]; z>=8: W2 [E][F][D] -> W2T [E][D][F].
// router: per-token eid/alpha/mu/rsig (+ atomicAdd cnt[e]). cnt/cnt2 zeroed by hipMemsetAsync before K1.
__global__ __launch_bounds__(256) void prep_kernel(
    const float* __restrict__ W1, const float* __restrict__ W2,
    ushort* __restrict__ W1T, ushort* __restrict__ W2T,
    const float* __restrict__ x, const float* __restrict__ cent,
    int* __restrict__ cnt, float* __restrict__ alphav, int* __restrict__ eidv,
    float* __restrict__ muv, float* __restrict__ rsigv) {
  __shared__ ushort tile[64][34];
  int bx = blockIdx.x;
  int tid = threadIdx.x;
  if (bx < 8192) {  // ---- convT tile ----
    int z = bx >> 9, idx = bx & 511;
    const float* src; ushort* dst; int R, C, c0, r0;
    if (z < E_NUM) {
      src = W1 + (size_t)z * D_DIM * F_DIM;
      dst = W1T + (size_t)z * D_DIM * F_DIM;
      R = D_DIM; C = F_DIM;
      c0 = (idx & 31) * 64; r0 = (idx >> 5) * 32;
    } else {
      src = W2 + (size_t)(z - E_NUM) * D_DIM * F_DIM;
      dst = W2T + (size_t)(z - E_NUM) * D_DIM * F_DIM;
      R = F_DIM; C = D_DIM;
      c0 = (idx & 7) * 64; r0 = (idx >> 3) * 32;
    }
    int tc = (tid & 31) * 2, tr = tid >> 5;
#pragma unroll
    for (int rr = 0; rr < 32; rr += 8) {
      float2 v = *(const float2*)(src + (size_t)(r0 + tr + rr) * C + c0 + tc);
      tile[tc][tr + rr] = f2bf(v.x);
      tile[tc + 1][tr + rr] = f2bf(v.y);
    }
    __syncthreads();
    int wc = tid >> 4, wj = (tid & 15) * 2;
#pragma unroll
    for (int cc = 0; cc < 64; cc += 16) {
      uint v = (uint)tile[cc + wc][wj] | ((uint)tile[cc + wc][wj + 1] << 16);
      *(uint*)(dst + (size_t)(c0 + cc + wc) * R + r0 + wj) = v;
    }
  } else {  // ---- router: 4 tokens per block ----
    int wave = tid >> 6, lane = tid & 63;
    int t = (bx - 8192) * 4 + wave;
    const float* xp = x + (size_t)t * D_DIM + lane * 8;
    float4 x0 = *(const float4*)xp, x1 = *(const float4*)(xp + 4);
    float xv[8] = {x0.x, x0.y, x0.z, x0.w, x1.x, x1.y, x1.z, x1.w};
    float s = 0.f, s2 = 0.f, cd[E_NUM];
#pragma unroll
    for (int j = 0; j < 8; j++) { s += xv[j]; s2 += xv[j] * xv[j]; }
#pragma unroll
    for (int e = 0; e < E_NUM; e++) {
      const float* cp = cent + (size_t)e * D_DIM + lane * 8;
      float4 c0 = *(const float4*)cp, c1 = *(const float4*)(cp + 4);
      float cv[8] = {c0.x, c0.y, c0.z, c0.w, c1.x, c1.y, c1.z, c1.w};
      float a = 0.f;
#pragma unroll
      for (int j = 0; j < 8; j++) a += xv[j] * cv[j];
      cd[e] = a;
    }
#pragma unroll
    for (int m = 1; m < 64; m <<= 1) {
      s  += __shfl_xor(s,  m, 64);
      s2 += __shfl_xor(s2, m, 64);
#pragma unroll
      for (int e = 0; e < E_NUM; e++) cd[e] += __shfl_xor(cd[e], m, 64);
    }
    if (lane == 0) {
      float mu = s / (float)D_DIM;
      float var = s2 / (float)D_DIM - mu * mu;
      if (var < 0.f) var = 0.f;
      int best = 0;
#pragma unroll
      for (int e = 1; e < E_NUM; e++) if (cd[e] > cd[best]) best = e;  // first-max (np.argmax)
      eidv[t] = best;
      alphav[t] = 1.f / (1.f + expf(-cd[best]));
      muv[t] = mu;
      rsigv[t] = rsqrtf(var + LN_EPS);
      atomicAdd(&cnt[best], 1);  // device-scope; complete at dispatch boundary
    }
  }
}

// ---------------- K2 scatter: LN apply -> compact sorted h0p (bf16), tok map ----------------
__global__ __launch_bounds__(256) void scatter_kernel(
    const float* __restrict__ x, const float* __restrict__ g, const float* __restrict__ b,
    const int* __restrict__ eidv, const float* __restrict__ muv, const float* __restrict__ rsigv,
    const int* __restrict__ cnt, int* __restrict__ cnt2,
    int* __restrict__ tok, ushort* __restrict__ h0p) {
  int wave = threadIdx.x >> 6, lane = threadIdx.x & 63;
  int t = blockIdx.x * 4 + wave;
  int e = eidv[t];
  int offs = 0;
#pragma unroll
  for (int i = 0; i < E_NUM; i++) offs += (i < e) ? cnt[i] : 0;
  int pos = 0;
  if (lane == 0) pos = atomicAdd(&cnt2[e], 1);
  pos = __shfl(pos, 0, 64);
  int srow = offs + pos;
  if (lane == 0) tok[srow] = t;
  float mu = muv[t], rs = rsigv[t];
  int c0 = lane * 8;
  const float* xp = x + (size_t)t * D_DIM + c0;
  const float* gp = g + (size_t)e * D_DIM + c0;
  const float* bp = b + (size_t)e * D_DIM + c0;
  union { ushort u16[8]; uint4 v; } o;
#pragma unroll
  for (int j = 0; j < 8; j++)
    o.u16[j] = f2bf((xp[j] - mu) * rs * gp[j] + bp[j]);
  *(uint4*)(h0p + (size_t)srow * D_DIM + c0) = o.v;
}

// ---------------- K5 reduce: out[t] = x[t] + alpha*(sum of 4 split-K partials + b2[e]) ----------------
// 256 threads handle 2 sorted rows; Part reads linear, out scatter by token.
__global__ __launch_bounds__(256) void reduce_kernel(
    const float* __restrict__ P, const float* __restrict__ x, const float* __restrict__ b2,
    const int* __restrict__ tok, const int* __restrict__ eidv, const float* __restrict__ alphav,
    float* __restrict__ out) {
  int srow = blockIdx.x * 2 + (threadIdx.x >> 7);
  int c = (threadIdx.x & 127) * 4;
  int t = tok[srow];
  int e = eidv[t];
  float al = alphav[t];
  const size_t stride = (size_t)T_TOK * D_DIM;
  const float* p = P + (size_t)srow * D_DIM + c;
  float4 s0 = *(const float4*)(p);
  float4 s1 = *(const float4*)(p + stride);
  float4 s2 = *(const float4*)(p + 2 * stride);
  float4 s3 = *(const float4*)(p + 3 * stride);
  float4 bv = *(const float4*)(b2 + (size_t)e * D_DIM + c);
  float4 xv = *(const float4*)(x + (size_t)t * D_DIM + c);
  float4 o;
  o.x = xv.x + al * (s0.x + s1.x + s2.x + s3.x + bv.x);
  o.y = xv.y + al * (s0.y + s1.y + s2.y + s3.y + bv.y);
  o.z = xv.z + al * (s0.z + s1.z + s2.z + s3.z + bv.z);
  o.w = xv.w + al * (s0.w + s1.w + s2.w + s3.w + bv.w);
  *(float4*)(out + (size_t)t * D_DIM + c) = o;
}

// ---------------- grouped GEMM, 128x128 tile, dbuf LDS, XOR swizzle, COMPACT rows ----------------
// A rows compact-sorted: expert e owns [offs_e, offs_e+ce). Row clamp => no poison reads.
// MODE 1: H[srow] = relu(A*W1 + b1) bf16.  KTOT=512,  bx = nt in [0,16).
// MODE 2: Part[slice][srow] = A*W2 slice-sum (raw f32). KTOT=2048, bx = slice*4 + nt.
template<int KTOT, int NTOT, int MODE>
__global__ __launch_bounds__(256) void moe_gemm_kernel(
    const ushort* __restrict__ A, const ushort* __restrict__ BT,
    const float* __restrict__ bias, const int* __restrict__ cnt,
    ushort* __restrict__ Hout, float* __restrict__ Pout) {
  constexpr int KITER = 8;  // 512-k window per block
  int e = blockIdx.z, mt = blockIdx.y;
  int cl[E_NUM];
#pragma unroll
  for (int i = 0; i < E_NUM; i++) cl[i] = cnt[i];
  int ce = cl[e];
  if (mt * 128 >= ce) return;  // uniform early-exit before any barrier
  int offs_e = 0;
#pragma unroll
  for (int i = 0; i < E_NUM; i++) offs_e += (i < e) ? cl[i] : 0;
  int bx = blockIdx.x;
  int nt = (MODE == 1) ? bx : (bx & 3);
  int k_base = (MODE == 1) ? 0 : (bx >> 2) * 512;
  int n0 = nt * 128;
  int rowbase = offs_e + mt * 128;
  int rowmax = offs_e + ce - 1;

  __shared__ ushort As[2][128 * 64];  // [buf][m][64], 16B cols XOR-swizzled by (m&7)
  __shared__ ushort Bs[2][128 * 64];

  int tid = threadIdx.x;
  int lane = tid & 63, wave = tid >> 6;
  int mw = (wave & 1) * 64, nw = (wave >> 1) * 64;  // wave's 64x64 sub-tile
  int fm = lane & 15, quad = lane >> 4;
  int fm7 = fm & 7;

  int srow = tid >> 3;                         // [0,32)
  int scol = (((tid & 7) ^ (srow & 7)) * 8);   // swizzled global col (16B units)
  const ushort* a_gp[4];
  const ushort* b_gp[4];
#pragma unroll
  for (int r = 0; r < 4; r++) {
    int ar = rowbase + r * 32 + srow;
    if (ar > rowmax) ar = rowmax;  // clamp inside expert region; masked on store
    a_gp[r] = A + (size_t)ar * KTOT + k_base + scol;
    b_gp[r] = BT + ((size_t)e * NTOT + n0 + r * 32 + srow) * KTOT + k_base + scol;
  }

  floatx4 acc[4][4];
#pragma unroll
  for (int i = 0; i < 4; i++)
#pragma unroll
    for (int j = 0; j < 4; j++) acc[i][j] = (floatx4){0.f, 0.f, 0.f, 0.f};

  auto stage = [&](int ki, int buf) {
    int k0 = ki * 64;
    char* al = (char*)As[buf] + wave * 1024;  // wave-uniform base (+ r*4096 per round)
    char* bl = (char*)Bs[buf] + wave * 1024;
#pragma unroll
    for (int r = 0; r < 4; r++) {
      gld_lds16(a_gp[r] + k0, al + r * 4096);
      gld_lds16(b_gp[r] + k0, bl + r * 4096);
    }
  };

  stage(0, 0);
  for (int ki = 0; ki < KITER; ki++) {
    __syncthreads();  // drains DMA(ki); separates compute(ki-1) from stage(ki+1)
    if (ki + 1 < KITER) stage(ki + 1, (ki + 1) & 1);
    const ushort* Ab = As[ki & 1];
    const ushort* Bb = Bs[ki & 1];
#pragma unroll
    for (int ks = 0; ks < 2; ks++) {
      int c8 = ((ks * 4 + quad) ^ fm7) * 8;  // unswizzle on read
      bf16x8 af[4], bfr[4];
#pragma unroll
      for (int i = 0; i < 4; i++) {
        af[i]  = *(const bf16x8*)(Ab + (mw + i * 16 + fm) * 64 + c8);
        bfr[i] = *(const bf16x8*)(Bb + (nw + i * 16 + fm) * 64 + c8);
      }
#pragma unroll
      for (int mi = 0; mi < 4; mi++)
#pragma unroll
        for (int ni = 0; ni < 4; ni++)
          acc[mi][ni] = __builtin_amdgcn_mfma_f32_16x16x32_bf16(af[mi], bfr[ni], acc[mi][ni], 0, 0, 0);
    }
  }

  // C/D layout: col = lane&15, row = quad*4 + reg (m89/m91 verified)
#pragma unroll
  for (int mi = 0; mi < 4; mi++) {
    int lmb = mt * 128 + mw + mi * 16 + quad * 4;
#pragma unroll
    for (int r = 0; r < 4; r++) {
      int lm = lmb + r;
      if (lm >= ce) continue;
      size_t row = (size_t)(offs_e + lm);
      if (MODE == 1) {
#pragma unroll
        for (int ni = 0; ni < 4; ni++) {
          int gcol = n0 + nw + ni * 16 + fm;
          float v = acc[mi][ni][r] + bias[e * NTOT + gcol];
          v = v > 0.f ? v : 0.f;
          Hout[row * NTOT + gcol] = f2bf(v);
        }
      } else {
        float* dst = Pout + (size_t)(bx >> 2) * T_TOK * NTOT + row * NTOT;
#pragma unroll
        for (int ni = 0; ni < 4; ni++)
          dst[n0 + nw + ni * 16 + fm] = acc[mi][ni][r];
      }
    }
  }
}

extern "C" void kernel_launch(void* const* d_in, const int* in_sizes, int n_in,
                              void* d_out, int out_size, void* d_ws, size_t ws_size,
                              hipStream_t stream) {
  const float* x    = (const float*)d_in[0];
  const float* cent = (const float*)d_in[1];
  const float* ln_g = (const float*)d_in[2];
  const float* ln_b = (const float*)d_in[3];
  const float* W1   = (const float*)d_in[4];
  const float* b1   = (const float*)d_in[5];
  const float* W2   = (const float*)d_in[6];
  const float* b2   = (const float*)d_in[7];
  float* out = (float*)d_out;

  char* ws = (char*)d_ws;
  size_t off = 0;
  auto alloc = [&](size_t bytes) {
    char* p = ws + off;
    off += (bytes + 255) & ~(size_t)255;
    return p;
  };
  int*    cnts   = (int*)alloc(2 * E_NUM * 4);                          // cnt | cnt2
  float*  alphav = (float*)alloc(T_TOK * 4);
  int*    eidv   = (int*)alloc(T_TOK * 4);
  float*  muv    = (float*)alloc(T_TOK * 4);
  float*  rsigv  = (float*)alloc(T_TOK * 4);
  int*    tok    = (int*)alloc(T_TOK * 4);
  ushort* h0p    = (ushort*)alloc((size_t)T_TOK * D_DIM * 2);           // 2 MB compact
  ushort* H      = (ushort*)alloc((size_t)T_TOK * F_DIM * 2);           // 8 MB compact
  ushort* W1T    = (ushort*)alloc((size_t)E_NUM * F_DIM * D_DIM * 2);   // 16.8 MB
  ushort* W2T    = (ushort*)alloc((size_t)E_NUM * D_DIM * F_DIM * 2);   // 16.8 MB
  float*  Part   = (float*)alloc((size_t)4 * T_TOK * D_DIM * 4);        // 16.8 MB f32
  int* cnt  = cnts;
  int* cnt2 = cnts + E_NUM;

  // 0) zero the counters (graph-capture-legal memset node)
  hipMemsetAsync(cnts, 0, 2 * E_NUM * 4, stream);
  // 1) prep: weight convT + router (+cnt histogram)
  hipLaunchKernelGGL(prep_kernel, dim3(8192 + T_TOK / 4), dim3(256), 0, stream,
                     W1, W2, W1T, W2T, x, cent, cnt, alphav, eidv, muv, rsigv);
  // 2) scatter: LN rows into compact sorted h0p
  hipLaunchKernelGGL(scatter_kernel, dim3(T_TOK / 4), dim3(256), 0, stream,
                     x, ln_g, ln_b, eidv, muv, rsigv, cnt, cnt2, tok, h0p);
  // 3) H = relu(h0 @ W1 + b1): 128x128 dbuf
  hipLaunchKernelGGL((moe_gemm_kernel<D_DIM, F_DIM, 1>),
                     dim3(F_DIM / 128, T_TOK / 128, E_NUM), dim3(256), 0, stream,
                     h0p, W1T, b1, cnt, H, nullptr);
  // 4) Part[slice] = H @ W2 partials: 128x128 dbuf, split-K=4
  hipLaunchKernelGGL((moe_gemm_kernel<F_DIM, D_DIM, 2>),
                     dim3(4 * 4, T_TOK / 128, E_NUM), dim3(256), 0, stream,
                     H, W2T, nullptr, cnt, nullptr, Part);
  // 5) out = x + alpha*(sum Part + b2)
  hipLaunchKernelGGL(reduce_kernel, dim3(T_TOK / 2), dim3(256), 0, stream,
                     Part, x, b2, tok, eidv, alphav, out);
}